// Round 1
// baseline (94.104 us; speedup 1.0000x reference)
//
#include <hip/hip_runtime.h>

// S4D kernel generation: K[h,l] = 2*Re( sum_n Ceff[h,n] * exp(dtA[h,n]*l) )
//   dtA = A*dt, A = -exp(log_A_real) + i*A_imag, dt = exp(log_dt)
//   Ceff = C * (exp(dtA)-1)/A
//
// Strategy: one block per h (grid=1024, block=256). Thread t computes the 16
// coalesced outputs l = t + 256*j. Per n we seed z = exp(dtA*t) once
// (transcendentals), then advance by the constant ratio w256 = exp(256*dtA)
// via complex multiply (6 FMA per (n,j) term). Seed/ratio phases are reduced
// mod 2pi in fp64 so fp32 sincos stays accurate at arguments up to ~2500 rad.

#define HD   1024
#define NS   32
#define LL   4096
#define BLK  256
#define NJ   (LL / BLK)   // 16

__global__ __launch_bounds__(BLK) void s4d_kernel(
    const float* __restrict__ log_dt,
    const float* __restrict__ C_ri,
    const float* __restrict__ log_A_real,
    const float* __restrict__ A_imag,
    float* __restrict__ K)
{
    const int h   = blockIdx.x;
    const int tid = threadIdx.x;

    __shared__ float  s_wr[NS], s_wi[NS];   // w256 = exp(256*dtA)
    __shared__ float  s_cr[NS], s_ci[NS];   // 2*Ceff
    __shared__ float  s_a[NS];              // Re(dtA)
    __shared__ double s_b[NS];              // Im(dtA), fp64 for phase reduction

    const double TWO_PI     = 6.283185307179586;
    const double INV_TWO_PI = 0.15915494309189535;

    if (tid < NS) {
        const int   n   = tid;
        const float dt  = expf(log_dt[h]);
        const float ar  = -expf(log_A_real[h * NS + n]);   // Re(A) = -0.5
        const float ai  = A_imag[h * NS + n];              // Im(A)
        const float a   = ar * dt;                         // Re(dtA)
        const double bd = (double)ai * (double)dt;         // Im(dtA)
        const float b   = (float)bd;

        // exp(dtA) - 1  (|b| <= ~9.8, fp32 sincos fine)
        const float e = expf(a);
        float sb, cb;
        sincosf(b, &sb, &cb);
        const float er = fmaf(e, cb, -1.0f);
        const float ei = e * sb;

        // (er + i*ei) / (ar + i*ai)
        const float den = fmaf(ar, ar, ai * ai);
        const float inv = 1.0f / den;
        const float fr  = fmaf(er, ar,  ei * ai) * inv;
        const float fi  = fmaf(ei, ar, -er * ai) * inv;

        const float Cr = C_ri[(h * NS + n) * 2 + 0];
        const float Ci = C_ri[(h * NS + n) * 2 + 1];
        s_cr[n] = 2.0f * fmaf(Cr, fr, -Ci * fi);   // 2*Re(Ceff)
        s_ci[n] = 2.0f * fmaf(Cr, fi,  Ci * fr);   // 2*Im(Ceff)

        // w256 = exp(256*dtA): phase reduced mod 2pi in fp64
        double ph = bd * 256.0;
        ph -= floor(ph * INV_TWO_PI) * TWO_PI;
        float sw, cw;
        sincosf((float)ph, &sw, &cw);
        const float e256 = expf(a * 256.0f);
        s_wr[n] = e256 * cw;
        s_wi[n] = e256 * sw;
        s_a[n]  = a;
        s_b[n]  = bd;
    }
    __syncthreads();

    float acc[NJ];
#pragma unroll
    for (int j = 0; j < NJ; ++j) acc[j] = 0.0f;

    for (int n = 0; n < NS; ++n) {
        const float  a = s_a[n];
        const double b = s_b[n];

        // seed z = exp(dtA * tid), phase reduced mod 2pi in fp64
        const float mag = expf(a * (float)tid);
        double ph = b * (double)tid;
        ph -= floor(ph * INV_TWO_PI) * TWO_PI;
        float sp, cp;
        sincosf((float)ph, &sp, &cp);
        float zr = mag * cp;
        float zi = mag * sp;

        const float wr = s_wr[n], wi = s_wi[n];
        const float cr = s_cr[n], ci = s_ci[n];

#pragma unroll
        for (int j = 0; j < NJ; ++j) {
            acc[j] = fmaf(cr, zr, fmaf(-ci, zi, acc[j]));
            const float t = fmaf(zr, wr, -zi * wi);
            zi = fmaf(zr, wi, zi * wr);
            zr = t;
        }
    }

    float* out = K + h * LL + tid;
#pragma unroll
    for (int j = 0; j < NJ; ++j) out[j * BLK] = acc[j];
}

extern "C" void kernel_launch(void* const* d_in, const int* in_sizes, int n_in,
                              void* d_out, int out_size, void* d_ws, size_t ws_size,
                              hipStream_t stream) {
    // d_in[0] = L (int scalar, == 4096, hard-coded)
    const float* log_dt     = (const float*)d_in[1];
    const float* C_ri       = (const float*)d_in[2];
    const float* log_A_real = (const float*)d_in[3];
    const float* A_imag     = (const float*)d_in[4];
    float* K = (float*)d_out;

    s4d_kernel<<<dim3(HD), dim3(BLK), 0, stream>>>(log_dt, C_ri, log_A_real, A_imag, K);
}

// Round 2
// 78.965 us; speedup vs baseline: 1.1917x; 1.1917x over previous
//
#include <hip/hip_runtime.h>

// S4D kernel generation: K[h,l] = 2*Re( sum_n Ceff[h,n] * exp(dtA[h,n]*l) )
//   dtA = A*dt, A = -exp(log_A_real) + i*A_imag, dt = exp(log_dt)
//   Ceff = C * (exp(dtA)-1)/A
//
// R2 structure: one block per h (grid=1024, block=256). Thread t owns the 16
// coalesced outputs l = t + 256*j. Key identities:
//   * z_j = exp(dtA*(t+256j)) is geometric with ratio w = exp(256*dtA).
//   * u_j = 2*Re(Ceff * z_j) obeys the REAL second-order recurrence
//       u_j = 2Re(w)*u_{j-1} - |w|^2*u_{j-2}
//     (w satisfies its characteristic polynomial), i.e. 3 real ops per (n,j)
//     instead of a 6-FMA complex multiply.
//   * n is processed in pairs packed into float2 ext-vectors so the backend
//     can select v_pk_fma_f32 (2x fp32 rate on gfx950).
//   * Seed phases reduced mod 1 revolution in fp64, then hardware
//     v_sin/v_cos via __sinf/__cosf (arg in [0,2pi)) — no ocml polynomial.

#define HD   1024
#define NS   32
#define LL   4096
#define BLK  256
#define NJ   (LL / BLK)   // 16

typedef float v2 __attribute__((ext_vector_type(2)));

__global__ __launch_bounds__(BLK) void s4d_kernel(
    const float* __restrict__ log_dt,
    const float* __restrict__ C_ri,
    const float* __restrict__ log_A_real,
    const float* __restrict__ A_imag,
    float* __restrict__ K)
{
    const int h   = blockIdx.x;
    const int tid = threadIdx.x;

    // Pair layout: slot (n&15)*2 + (n>>4) so pair np holds n=np (x) and n=np+16 (y).
    __shared__ v2 s_wr[NS / 2], s_wi[NS / 2];     // w = exp(256*dtA)
    __shared__ v2 s_q[NS / 2];                    // |w|^2
    __shared__ v2 s_c2r[NS / 2], s_c2i[NS / 2];   // 2*Ceff
    __shared__ v2 s_al2[NS / 2];                  // Re(dtA)*log2(e)
    __shared__ double s_rb[NS];                   // Im(dtA)/(2pi), plain index n

    const double TWO_PI     = 6.283185307179586;
    const double INV_TWO_PI = 0.15915494309189535;
    const float  TWO_PI_F   = 6.2831853f;

    if (tid < NS) {
        const int   n   = tid;
        const int   sl  = ((n & 15) << 1) | (n >> 4);
        const float dt  = expf(log_dt[h]);
        const float ar  = -expf(log_A_real[h * NS + n]);   // Re(A)
        const float ai  = A_imag[h * NS + n];              // Im(A)
        const float a   = ar * dt;                         // Re(dtA)
        const double bd = (double)ai * (double)dt;         // Im(dtA)
        const float b   = (float)bd;

        // exp(dtA) - 1
        const float e = expf(a);
        float sb, cb;
        sincosf(b, &sb, &cb);
        const float er = fmaf(e, cb, -1.0f);
        const float ei = e * sb;

        // (er + i*ei) / (ar + i*ai)
        const float den = fmaf(ar, ar, ai * ai);
        const float inv = 1.0f / den;
        const float fr  = fmaf(er, ar,  ei * ai) * inv;
        const float fi  = fmaf(ei, ar, -er * ai) * inv;

        const float Cr = C_ri[(h * NS + n) * 2 + 0];
        const float Ci = C_ri[(h * NS + n) * 2 + 1];
        ((float*)s_c2r)[sl] = 2.0f * fmaf(Cr, fr, -Ci * fi);
        ((float*)s_c2i)[sl] = 2.0f * fmaf(Cr, fi,  Ci * fr);

        // w = exp(256*dtA), phase reduced mod 2pi in fp64
        double ph = bd * 256.0;
        ph -= floor(ph * INV_TWO_PI) * TWO_PI;
        float sw, cw;
        sincosf((float)ph, &sw, &cw);
        const float e256 = expf(a * 256.0f);
        ((float*)s_wr)[sl]  = e256 * cw;
        ((float*)s_wi)[sl]  = e256 * sw;
        ((float*)s_q)[sl]   = e256 * e256;
        ((float*)s_al2)[sl] = a * 1.4426950408889634f;
        s_rb[n] = bd * INV_TWO_PI;   // revolutions per unit l
    }
    __syncthreads();

    v2 acc[NJ];
#pragma unroll
    for (int j = 0; j < NJ; ++j) acc[j] = (v2)(0.0f);

    const float t = (float)tid;

    for (int np = 0; np < NS / 2; ++np) {
        const v2 al2 = s_al2[np];
        const v2 wr  = s_wr[np];
        const v2 wi  = s_wi[np];
        const v2 q   = s_q[np];
        const v2 c2r = s_c2r[np];
        const v2 c2i = s_c2i[np];

        // seed z = exp(dtA*t): magnitude via hw exp2, phase reduced in fp64
        v2 mag;
        mag.x = __builtin_amdgcn_exp2f(al2.x * t);
        mag.y = __builtin_amdgcn_exp2f(al2.y * t);

        double r0 = s_rb[np] * (double)tid;        r0 -= floor(r0);
        double r1 = s_rb[np + 16] * (double)tid;   r1 -= floor(r1);
        const float f0 = (float)r0 * TWO_PI_F;
        const float f1 = (float)r1 * TWO_PI_F;

        v2 zr, zi;
        zr.x = mag.x * __cosf(f0);
        zr.y = mag.y * __cosf(f1);
        zi.x = mag.x * __sinf(f0);
        zi.y = mag.y * __sinf(f1);

        // u0 = 2Re(Ceff*z), u1 = 2Re(Ceff*z*w)
        v2 u0 = c2r * zr - c2i * zi;
        v2 zwr = zr * wr - zi * wi;
        v2 zwi = zr * wi + zi * wr;
        v2 u1 = c2r * zwr - c2i * zwi;
        const v2 p = wr + wr;   // 2*Re(w)

        acc[0] += u0;
        acc[1] += u1;
#pragma unroll
        for (int j = 2; j < NJ; ++j) {
            const v2 u = p * u1 - q * u0;
            acc[j] += u;
            u0 = u1;
            u1 = u;
        }
    }

    float* out = K + h * LL + tid;
#pragma unroll
    for (int j = 0; j < NJ; ++j) out[j * BLK] = acc[j].x + acc[j].y;
}

extern "C" void kernel_launch(void* const* d_in, const int* in_sizes, int n_in,
                              void* d_out, int out_size, void* d_ws, size_t ws_size,
                              hipStream_t stream) {
    // d_in[0] = L (int scalar, == 4096, hard-coded)
    const float* log_dt     = (const float*)d_in[1];
    const float* C_ri       = (const float*)d_in[2];
    const float* log_A_real = (const float*)d_in[3];
    const float* A_imag     = (const float*)d_in[4];
    float* K = (float*)d_out;

    s4d_kernel<<<dim3(HD), dim3(BLK), 0, stream>>>(log_dt, C_ri, log_A_real, A_imag, K);
}